// Round 1
// 69.969 us; speedup vs baseline: 1.0998x; 1.0998x over previous
//
#include <hip/hip_runtime.h>

// 5-qubit state, two patches per thread packed in float2 lanes (.x = patch0, .y = patch1).
// index = a*16 + b*8 + c*4 + d*2 + e ; wire0=a=bit4 ... wire4=e=bit0
// All gates are elementwise identical across the two packed patches -> v_pk_*_f32.

typedef float f2 __attribute__((ext_vector_type(2)));

__device__ __forceinline__ f2 pk_fma(f2 a, f2 b, f2 c) {
    f2 d;
    asm("v_pk_fma_f32 %0, %1, %2, %3" : "=v"(d) : "v"(a), "v"(b), "v"(c));
    return d;
}
__device__ __forceinline__ f2 pk_mul(f2 a, f2 b) {
    f2 d;
    asm("v_pk_mul_f32 %0, %1, %2" : "=v"(d) : "v"(a), "v"(b));
    return d;
}
__device__ __forceinline__ f2 sp(float v) { f2 r; r.x = v; r.y = v; return r; }

// sin/cos of ang/2 via native v_sin/v_cos (input in revolutions; |rev|<0.5 here).
__device__ __forceinline__ void sc_half(float ang, float& s, float& c) {
    const float r = ang * 0.07957747154594767f;   // (ang/2) / (2*pi)
    s = __builtin_amdgcn_sinf(r);
    c = __builtin_amdgcn_cosf(r);
}
__device__ __forceinline__ void sc_full(float ang, float& s, float& c) {
    const float r = ang * 0.15915494309189535f;   // ang / (2*pi)
    s = __builtin_amdgcn_sinf(r);
    c = __builtin_amdgcn_cosf(r);
}
__device__ __forceinline__ void sc_half2(f2 ang, f2& s, f2& c) {
    float s0, c0, s1, c1;
    sc_half(ang.x, s0, c0);
    sc_half(ang.y, s1, c1);
    s.x = s0; s.y = s1; c.x = c0; c.y = c1;
}

template<int BIT>
__device__ __forceinline__ void apply_rx(f2 (&R)[32], f2 (&I)[32],
                                         f2 c, f2 s, f2 ns) {
    // gate [[c, -i*s], [-i*s, c]]  (elementwise over packed patch pair)
#pragma unroll
    for (int m = 0; m < 16; ++m) {
        const int lo = m & ((1 << BIT) - 1);
        const int hi = (m >> BIT) << (BIT + 1);
        const int i0 = hi | lo;
        const int i1 = i0 | (1 << BIT);
        const f2 ar = R[i0], ai = I[i0];
        const f2 br = R[i1], bi = I[i1];
        R[i0] = pk_fma(c, ar, pk_mul(s,  bi));
        I[i0] = pk_fma(c, ai, pk_mul(ns, br));
        R[i1] = pk_fma(c, br, pk_mul(s,  ai));
        I[i1] = pk_fma(c, bi, pk_mul(ns, ar));
    }
}

// controlled-X_theta; NB=8 acts on the lower 16 amps only (used for layer 0
// where the wire-0 halves are still identical), NB=16 acts on all 32.
template<int CBIT, int TBIT, int NB>
__device__ __forceinline__ void cu_gate(f2 (&R)[32], f2 (&I)[32],
                                        float sn, float cs) {
    // u01 = sin - i*cos ; u10 = -sin - i*cos   (of theta/2)
    const f2 u01r = sp(sn),  u01i = sp(-cs), nu01i = sp(cs);
    const f2 u10r = sp(-sn), u10i = sp(-cs), nu10i = sp(cs);
#pragma unroll
    for (int m = 0; m < NB; ++m) {
        const int lo = m & ((1 << TBIT) - 1);
        const int hi = (m >> TBIT) << (TBIT + 1);
        const int i0 = hi | lo;
        if (!(i0 & (1 << CBIT))) continue;   // compile-time eliminated
        const int i1 = i0 | (1 << TBIT);
        const f2 ar = R[i0], ai = I[i0];
        const f2 br = R[i1], bi = I[i1];
        R[i0] = pk_fma(u01r, br, pk_mul(nu01i, bi));
        I[i0] = pk_fma(u01r, bi, pk_mul(u01i,  br));
        R[i1] = pk_fma(u10r, ar, pk_mul(nu10i, ai));
        I[i1] = pk_fma(u10r, ai, pk_mul(u10i,  ar));
    }
}

__global__ __launch_bounds__(256)
void qsim_kernel(const float* __restrict__ x,
                 const float* __restrict__ thetas,
                 const float* __restrict__ phis,
                 float* __restrict__ out, int P) {
    const int t = blockIdx.x * blockDim.x + threadIdx.x;
    const int T = P >> 1;                 // two patches per thread
    if (t >= T) return;

    // patches p0 = 2t, p1 = 2t+1 (adjacent j -> one float4 load covers both)
    const int b  = t >> 13;
    const int i  = (t & 8191) >> 6;
    const int jt = t & 63;

    // pix[k] = (patch0 angle, patch1 angle), k = 4*c + 2*dy + dx
    f2 pix[12];
    const float4* __restrict__ x4 = (const float4*)x;
#pragma unroll
    for (int c = 0; c < 3; ++c) {
#pragma unroll
        for (int dy = 0; dy < 2; ++dy) {
            const long row = ((long)(b * 3 + c) * 256 + (2 * i + dy));
            const float4 v = x4[row * 64 + jt];
            f2 a0; a0.x = v.x; a0.y = v.z;
            f2 a1; a1.x = v.y; a1.y = v.w;
            pix[c * 4 + dy * 2 + 0] = a0;
            pix[c * 4 + dy * 2 + 1] = a1;
        }
    }

    // ---- fold H(wire0) + layer-1 RX into 16-amp product state ----
    // amp(bcde) = m(bcde) * (-i)^popcount(bcde); wire-0 halves identical,
    // so keep only 16 amps until the first CPhase.
    f2 R[32], I[32];
    {
        f2 s1, c1, s2, c2, s3, c3, s4, c4;
        sc_half2(pix[0], s1, c1);
        sc_half2(pix[1], s2, c2);
        sc_half2(pix[2], s3, c3);
        sc_half2(pix[3], s4, c4);
        f2 pA[4], pB[4];
        pA[0] = pk_mul(c1, c2); pA[1] = pk_mul(c1, s2);
        pA[2] = pk_mul(s1, c2); pA[3] = pk_mul(s1, s2);
        pB[0] = pk_mul(c3, c4); pB[1] = pk_mul(c3, s4);
        pB[2] = pk_mul(s3, c4); pB[3] = pk_mul(s3, s4);
#pragma unroll
        for (int m = 0; m < 16; ++m) {
            const f2 v  = pk_mul(pA[m >> 2], pB[m & 3]);
            const f2 nv = -v;
            const f2 z  = sp(0.f);
            const int pc = __builtin_popcount((unsigned)m) & 3;
            R[m] = (pc == 0) ? v  : ((pc == 2) ? nv : z);
            I[m] = (pc == 1) ? nv : ((pc == 3) ? v  : z);
        }
    }

    // ---- layer 0: CU gates on 16 amps (halves still identical) ----
    {
        float sn, cs;
        sc_half(thetas[0], sn, cs); cu_gate<3, 2, 8>(R, I, sn, cs);
        sc_half(thetas[1], sn, cs); cu_gate<2, 1, 8>(R, I, sn, cs);
        sc_half(thetas[2], sn, cs); cu_gate<1, 0, 8>(R, I, sn, cs);
        sc_half(thetas[3], sn, cs); cu_gate<0, 3, 8>(R, I, sn, cs);
    }
    // duplicate to wire0=1 half with CPhase(phi0) folded in (amps 24..31)
    {
        float snp, csp;
        sc_full(phis[0], snp, csp);
        const f2 cp = sp(csp), spp = sp(snp), np = sp(-snp);
#pragma unroll
        for (int m = 0; m < 8; ++m) { R[m + 16] = R[m]; I[m + 16] = I[m]; }
#pragma unroll
        for (int m = 8; m < 16; ++m) {
            R[m + 16] = pk_fma(cp, R[m], pk_mul(np,  I[m]));
            I[m + 16] = pk_fma(cp, I[m], pk_mul(spp, R[m]));
        }
    }

    // ---- layers 1,2 on full 32-amp state ----
#pragma unroll
    for (int L = 1; L < 3; ++L) {
        f2 s2v, c2v;
        sc_half2(pix[4 * L + 0], s2v, c2v); apply_rx<3>(R, I, c2v, s2v, -s2v);
        sc_half2(pix[4 * L + 1], s2v, c2v); apply_rx<2>(R, I, c2v, s2v, -s2v);
        sc_half2(pix[4 * L + 2], s2v, c2v); apply_rx<1>(R, I, c2v, s2v, -s2v);
        sc_half2(pix[4 * L + 3], s2v, c2v); apply_rx<0>(R, I, c2v, s2v, -s2v);
        {
            float sn, cs;
            sc_half(thetas[4 * L + 0], sn, cs); cu_gate<3, 2, 16>(R, I, sn, cs);
            sc_half(thetas[4 * L + 1], sn, cs); cu_gate<2, 1, 16>(R, I, sn, cs);
            sc_half(thetas[4 * L + 2], sn, cs); cu_gate<1, 0, 16>(R, I, sn, cs);
            sc_half(thetas[4 * L + 3], sn, cs); cu_gate<0, 3, 16>(R, I, sn, cs);
        }
        {
            float snp, csp;
            sc_full(phis[L], snp, csp);
            const f2 cp = sp(csp), spp = sp(snp), np = sp(-snp);
#pragma unroll
            for (int m = 24; m < 32; ++m) {
                const f2 r = R[m], ii = I[m];
                R[m] = pk_fma(cp, r,  pk_mul(np,  ii));
                I[m] = pk_fma(cp, ii, pk_mul(spp, r));
            }
        }
    }

    // final H on wire0 + <Z0>: ev = sum_m Re(v_m * conj(v_{m+16}))
    f2 ev = sp(0.f);
#pragma unroll
    for (int m = 0; m < 16; ++m) {
        ev = pk_fma(R[m], R[m + 16], pk_fma(I[m], I[m + 16], ev));
    }
    float2 o; o.x = ev.x; o.y = ev.y;
    reinterpret_cast<float2*>(out)[t] = o;
}

extern "C" void kernel_launch(void* const* d_in, const int* in_sizes, int n_in,
                              void* d_out, int out_size, void* d_ws, size_t ws_size,
                              hipStream_t stream) {
    const float* x      = (const float*)d_in[0];
    const float* thetas = (const float*)d_in[1];
    const float* phis   = (const float*)d_in[2];
    float* out = (float*)d_out;
    const int P = out_size;               // 16 * 128 * 128 = 262144
    const int T = P >> 1;                 // two patches per thread
    const int threads = 256;
    const int blocks = (T + threads - 1) / threads;
    qsim_kernel<<<blocks, threads, 0, stream>>>(x, thetas, phis, out, P);
}